// Round 5
// baseline (562.163 us; speedup 1.0000x reference)
//
#include <hip/hip_runtime.h>
#include <hip/hip_bf16.h>

#define NS 65536
#define NQ 131072
#define DD 256
#define NC 1024
#define BM 16
#define LCAP 128

typedef __attribute__((ext_vector_type(8))) short short8;
typedef __attribute__((ext_vector_type(4))) float f32x4;

// LDS carve (bytes). Image [16][1024] f32 at 0 (A[16][256]bf16 overlaid at 0,
// dead before image is written). Misc above 64K. Total ~66 KB -> 2 blocks/CU.
#define SMEM_QI    65536
#define SMEM_RED   65600
#define SMEM_ROWM  65856
#define SMEM_ROWL  65920
#define SMEM_TOTAL 65984

static __device__ __forceinline__ unsigned short f2bf(float f) {
    unsigned int u = __float_as_uint(f);
    u += 0x7fffu + ((u >> 16) & 1u);          // round-to-nearest-even
    return (unsigned short)(u >> 16);
}

// K1: one sf pass: per-row rinv (wave per row) + per-class compact row list.
__global__ __launch_bounds__(256) void k_count(const float* __restrict__ sf,
                                               const int* __restrict__ labels,
                                               float* __restrict__ rinv,
                                               int* __restrict__ cnts,
                                               int* __restrict__ lists) {
    const int row  = (blockIdx.x << 2) + (threadIdx.x >> 6);
    const int lane = threadIdx.x & 63;
    float4 v = *reinterpret_cast<const float4*>(sf + (size_t)row * DD + lane * 4);
    float ss = v.x*v.x + v.y*v.y + v.z*v.z + v.w*v.w;
#pragma unroll
    for (int off = 32; off; off >>= 1) ss += __shfl_xor(ss, off);
    if (lane == 0) {
        rinv[row] = 1.0f / fmaxf(sqrtf(ss), 1e-8f);
        const int lab = labels[row];
        const int slot = atomicAdd(&cnts[lab], 1);
        if (slot < LCAP) lists[lab * LCAP + slot] = row;
    }
}

// K2: block per class, gather listed rows, mean -> l2norm -> bf16 + arange tail.
__global__ __launch_bounds__(256) void k_proto(const float* __restrict__ sf,
                                               const float* __restrict__ rinv,
                                               const int* __restrict__ cnts,
                                               const int* __restrict__ lists,
                                               unsigned short* __restrict__ pb,
                                               float* __restrict__ outTail) {
    __shared__ float red[4];
    const int c = blockIdx.x;
    const int t = threadIdx.x;
    const int total = cnts[c];
    const int n = min(total, LCAP);
    float acc = 0.f;
    for (int j = 0; j < n; ++j) {
        const int row = lists[c * LCAP + j];
        acc += sf[(size_t)row * DD + t] * rinv[row];
    }
    const float m = acc / fmaxf((float)total, 1.0f);
    float ss = m * m;
#pragma unroll
    for (int off = 32; off; off >>= 1) ss += __shfl_xor(ss, off);
    if ((t & 63) == 0) red[t >> 6] = ss;
    __syncthreads();
    const float tot = red[0] + red[1] + red[2] + red[3];
    const float r = 1.0f / fmaxf(sqrtf(tot), 1e-8f);
    pb[(size_t)c * DD + t] = f2bf(m * r);
    if (t == 0) outTail[c] = (float)c;
}

// K3: fused GEMM + qnorm + log_softmax. 256 thr = 4 waves, BM=16 rows/block,
// 2 blocks/CU. B loaded straight from L2 into a register double-buffer
// (no B LDS). 16 passes of 64 cols (wave w owns cols p*64 + w*16 + r16).
__global__ __launch_bounds__(256, 2) void k_gemm_lsm(const float* __restrict__ qf,
                                                     const unsigned short* __restrict__ pb,
                                                     float* __restrict__ out) {
    extern __shared__ char smem[];
    const int tid  = threadIdx.x;
    const int w    = tid >> 6;
    const int lane = tid & 63;
    const int g    = lane >> 4;
    const int r16  = lane & 15;
    const size_t qbase = (size_t)blockIdx.x * BM;
    const char* pbB = (const char*)pb;

    // prologue: cooperative A-stage (16 rows x 256 dims), qinv en route
    {
        const int row = tid >> 4;           // 0..15
        const int seg = tid & 15;
        const float* qrow = qf + (qbase + row) * (size_t)DD + seg * 16;
        float4 f0 = *reinterpret_cast<const float4*>(qrow + 0);
        float4 f1 = *reinterpret_cast<const float4*>(qrow + 4);
        float4 f2 = *reinterpret_cast<const float4*>(qrow + 8);
        float4 f3 = *reinterpret_cast<const float4*>(qrow + 12);
        float ss = f0.x*f0.x + f0.y*f0.y + f0.z*f0.z + f0.w*f0.w
                 + f1.x*f1.x + f1.y*f1.y + f1.z*f1.z + f1.w*f1.w
                 + f2.x*f2.x + f2.y*f2.y + f2.z*f2.z + f2.w*f2.w
                 + f3.x*f3.x + f3.y*f3.y + f3.z*f3.z + f3.w*f3.w;
        ss += __shfl_xor(ss, 1); ss += __shfl_xor(ss, 2);
        ss += __shfl_xor(ss, 4); ss += __shfl_xor(ss, 8);
        short8 h0, h1;
        h0[0]=(short)f2bf(f0.x); h0[1]=(short)f2bf(f0.y); h0[2]=(short)f2bf(f0.z); h0[3]=(short)f2bf(f0.w);
        h0[4]=(short)f2bf(f1.x); h0[5]=(short)f2bf(f1.y); h0[6]=(short)f2bf(f1.z); h0[7]=(short)f2bf(f1.w);
        h1[0]=(short)f2bf(f2.x); h1[1]=(short)f2bf(f2.y); h1[2]=(short)f2bf(f2.z); h1[3]=(short)f2bf(f2.w);
        h1[4]=(short)f2bf(f3.x); h1[5]=(short)f2bf(f3.y); h1[6]=(short)f2bf(f3.z); h1[7]=(short)f2bf(f3.w);
        const int x = row & 7;
        char* aRow = smem + row * 512;
        *reinterpret_cast<short8*>(aRow + (((seg*2)     ^ x) << 4)) = h0;
        *reinterpret_cast<short8*>(aRow + (((seg*2 + 1) ^ x) << 4)) = h1;
        if (seg == 0)
            reinterpret_cast<float*>(smem + SMEM_QI)[row] = 1.0f / fmaxf(sqrtf(ss), 1e-8f);
    }
    __syncthreads();

    // hoist A frags: 32 VGPRs (row = r16)
    short8 a[8];
#pragma unroll
    for (int kk = 0; kk < 8; ++kk) {
        const int chunk = (kk * 4 + g) ^ (r16 & 7);
        a[kk] = *reinterpret_cast<const short8*>(smem + r16 * 512 + chunk * 16);
    }

    f32x4 acc[16];
#pragma unroll
    for (int p = 0; p < 16; ++p) acc[p] = (f32x4){0.f, 0.f, 0.f, 0.f};

    const int colW = w * 16 + r16;
    const int bOff = (4 * (0) + g) << 4;   // dummy to keep pattern obvious
    (void)bOff;

    // register double-buffered B stream straight from L2
    short8 b0[8], b1[8];
#pragma unroll
    for (int kk = 0; kk < 8; ++kk)
        b0[kk] = *reinterpret_cast<const short8*>(pbB + ((size_t)(0 * 64 + colW) << 9) + ((kk * 4 + g) << 4));

#pragma unroll
    for (int p = 0; p < 16; ++p) {
        if (p + 1 < 16) {
            if (p & 1) {
#pragma unroll
                for (int kk = 0; kk < 8; ++kk)
                    b0[kk] = *reinterpret_cast<const short8*>(pbB + ((size_t)((p + 1) * 64 + colW) << 9) + ((kk * 4 + g) << 4));
            } else {
#pragma unroll
                for (int kk = 0; kk < 8; ++kk)
                    b1[kk] = *reinterpret_cast<const short8*>(pbB + ((size_t)((p + 1) * 64 + colW) << 9) + ((kk * 4 + g) << 4));
            }
        }
        if (p & 1) {
#pragma unroll
            for (int kk = 0; kk < 8; ++kk)
                acc[p] = __builtin_amdgcn_mfma_f32_16x16x32_bf16(a[kk], b1[kk], acc[p], 0, 0, 0);
        } else {
#pragma unroll
            for (int kk = 0; kk < 8; ++kk)
                acc[p] = __builtin_amdgcn_mfma_f32_16x16x32_bf16(a[kk], b0[kk], acc[p], 0, 0, 0);
        }
    }
    __syncthreads();   // all waves past A reads; A region becomes the out image

    // ---- epilogue: qinv scale + row log_softmax (rows 0..15) ----
    float* qinvLds = reinterpret_cast<float*>(smem + SMEM_QI);
    float (*red)[4] = reinterpret_cast<float(*)[4]>(smem + SMEM_RED);
    float* rowM = reinterpret_cast<float*>(smem + SMEM_ROWM);
    float* rowL = reinterpret_cast<float*>(smem + SMEM_ROWL);

    float qi[4];
#pragma unroll
    for (int j = 0; j < 4; ++j) qi[j] = qinvLds[g * 4 + j];

#pragma unroll
    for (int p = 0; p < 16; ++p)
#pragma unroll
        for (int j = 0; j < 4; ++j) acc[p][j] *= qi[j];

    float rmax[4];
#pragma unroll
    for (int j = 0; j < 4; ++j) {
        float v = acc[0][j];
#pragma unroll
        for (int p = 1; p < 16; ++p) v = fmaxf(v, acc[p][j]);
#pragma unroll
        for (int off = 1; off < 16; off <<= 1) v = fmaxf(v, __shfl_xor(v, off));
        rmax[j] = v;
    }
    if (r16 == 0) {
#pragma unroll
        for (int j = 0; j < 4; ++j) red[g * 4 + j][w] = rmax[j];
    }
    __syncthreads();
    if (tid < 16) {
        float v = red[tid][0];
#pragma unroll
        for (int k = 1; k < 4; ++k) v = fmaxf(v, red[tid][k]);
        rowM[tid] = v;
    }
    __syncthreads();

    float rsum[4];
#pragma unroll
    for (int j = 0; j < 4; ++j) {
        const float rm = rowM[g * 4 + j];
        float s = 0.f;
#pragma unroll
        for (int p = 0; p < 16; ++p) s += __expf(acc[p][j] - rm);
#pragma unroll
        for (int off = 1; off < 16; off <<= 1) s += __shfl_xor(s, off);
        rsum[j] = s;
    }
    if (r16 == 0) {
#pragma unroll
        for (int j = 0; j < 4; ++j) red[g * 4 + j][w] = rsum[j];
    }
    __syncthreads();
    if (tid < 16) {
        float s = red[tid][0];
#pragma unroll
        for (int k = 1; k < 4; ++k) s += red[tid][k];
        rowL[tid] = rowM[tid] + __logf(s);
    }
    __syncthreads();

    // final values -> [16][1024] f32 LDS image
#pragma unroll
    for (int j = 0; j < 4; ++j) {
        const float sub = rowL[g * 4 + j];
        float* lrow = reinterpret_cast<float*>(smem) + (g * 4 + j) * NC;
#pragma unroll
        for (int p = 0; p < 16; ++p)
            lrow[p * 64 + colW] = acc[p][j] - sub;
    }
    __syncthreads();

    // coalesced dwordx4 stores: thread t -> row t>>4, chunks (t&15)+16s
    {
        const int orow = tid >> 4;
        const int rr = tid & 15;
        float* gout = out + (qbase + orow) * (size_t)NC;
#pragma unroll
        for (int s = 0; s < 16; ++s) {
            f32x4 v = *reinterpret_cast<const f32x4*>(smem + orow * 4096 + (s * 16 + rr) * 16);
            *reinterpret_cast<f32x4*>(gout + (s * 16 + rr) * 4) = v;
        }
    }
}

extern "C" void kernel_launch(void* const* d_in, const int* in_sizes, int n_in,
                              void* d_out, int out_size, void* d_ws, size_t ws_size,
                              hipStream_t stream) {
    const float* sf     = (const float*)d_in[0];
    const int*   labels = (const int*)d_in[1];
    const float* qf     = (const float*)d_in[2];
    float* out = (float*)d_out;

    char* ws = (char*)d_ws;
    float* rinv         = (float*)ws;                          // 256 KiB
    unsigned short* pb  = (unsigned short*)(ws + 262144);      // 512 KiB
    int* cnts           = (int*)(ws + 786432);                 // 4 KiB
    int* lists          = (int*)(ws + 790528);                 // 512 KiB

    hipFuncSetAttribute(reinterpret_cast<const void*>(k_gemm_lsm),
                        hipFuncAttributeMaxDynamicSharedMemorySize, SMEM_TOTAL);

    hipMemsetAsync(cnts, 0, NC * sizeof(int), stream);

    k_count<<<NS / 4, 256, 0, stream>>>(sf, labels, rinv, cnts, lists);

    float* outTail = out + (size_t)out_size - NC;
    k_proto<<<NC, 256, 0, stream>>>(sf, rinv, cnts, lists, pb, outTail);

    k_gemm_lsm<<<NQ / BM, 256, SMEM_TOTAL, stream>>>(qf, pb, out);
}

// Round 6
// 399.366 us; speedup vs baseline: 1.4076x; 1.4076x over previous
//
#include <hip/hip_runtime.h>
#include <hip/hip_bf16.h>

#define NS 65536
#define NQ 131072
#define DD 256
#define NC 1024
#define BM 16
#define LCAP 128

typedef __attribute__((ext_vector_type(8))) short short8;
typedef __attribute__((ext_vector_type(4))) float f32x4;

// LDS carve (bytes): A [16 rows][512B] at 0; B: 8 waves x 2 bufs x 4KB at 8192;
// qinv; redM; redS. Total 74816 -> 2 blocks/CU.
#define SMEM_B     8192
#define SMEM_QI    73728
#define SMEM_REDM  73792
#define SMEM_REDS  74304
#define SMEM_TOTAL 74816

static __device__ __forceinline__ unsigned short f2bf(float f) {
    unsigned int u = __float_as_uint(f);
    u += 0x7fffu + ((u >> 16) & 1u);          // round-to-nearest-even
    return (unsigned short)(u >> 16);
}

static __device__ __forceinline__ void gload_lds16(const void* src, void* dst) {
    using GPtr = const __attribute__((address_space(1))) unsigned int*;
    using LPtr = __attribute__((address_space(3))) unsigned int*;
    GPtr g = reinterpret_cast<GPtr>(reinterpret_cast<uintptr_t>(src));
    LPtr l = reinterpret_cast<LPtr>(static_cast<unsigned int>(reinterpret_cast<uintptr_t>(dst)));
    __builtin_amdgcn_global_load_lds(g, l, 16, 0, 0);
}

// K1: one sf pass: per-row rinv (wave per row) + per-class compact row list.
__global__ __launch_bounds__(256) void k_count(const float* __restrict__ sf,
                                               const int* __restrict__ labels,
                                               float* __restrict__ rinv,
                                               int* __restrict__ cnts,
                                               int* __restrict__ lists) {
    const int row  = (blockIdx.x << 2) + (threadIdx.x >> 6);
    const int lane = threadIdx.x & 63;
    float4 v = *reinterpret_cast<const float4*>(sf + (size_t)row * DD + lane * 4);
    float ss = v.x*v.x + v.y*v.y + v.z*v.z + v.w*v.w;
#pragma unroll
    for (int off = 32; off; off >>= 1) ss += __shfl_xor(ss, off);
    if (lane == 0) {
        rinv[row] = 1.0f / fmaxf(sqrtf(ss), 1e-8f);
        const int lab = labels[row];
        const int slot = atomicAdd(&cnts[lab], 1);
        if (slot < LCAP) lists[lab * LCAP + slot] = row;
    }
}

// K2: block per class, gather listed rows, mean -> l2norm -> bf16 + arange tail.
__global__ __launch_bounds__(256) void k_proto(const float* __restrict__ sf,
                                               const float* __restrict__ rinv,
                                               const int* __restrict__ cnts,
                                               const int* __restrict__ lists,
                                               unsigned short* __restrict__ pb,
                                               float* __restrict__ outTail) {
    __shared__ float red[4];
    const int c = blockIdx.x;
    const int t = threadIdx.x;
    const int total = cnts[c];
    const int n = min(total, LCAP);
    float acc = 0.f;
    for (int j = 0; j < n; ++j) {
        const int row = lists[c * LCAP + j];
        acc += sf[(size_t)row * DD + t] * rinv[row];
    }
    const float m = acc / fmaxf((float)total, 1.0f);
    float ss = m * m;
#pragma unroll
    for (int off = 32; off; off >>= 1) ss += __shfl_xor(ss, off);
    if ((t & 63) == 0) red[t >> 6] = ss;
    __syncthreads();
    const float tot = red[0] + red[1] + red[2] + red[3];
    const float r = 1.0f / fmaxf(sqrtf(tot), 1e-8f);
    pb[(size_t)c * DD + t] = f2bf(m * r);
    if (t == 0) outTail[c] = (float)c;
}

// K3: fused GEMM + qnorm + log_softmax. 512 thr = 8 waves, BM=16 rows, 2 blk/CU.
// Swapped MFMA: acc = mfma(b, a, acc) -> thread (g,r16) reg j holds
// logits[query r16][class base + g*4 + j]. Stores go straight from acc.
// Wave w owns classes u-pass p*128 + w*16 .. +16; 16 stage-units of 4KB
// (16 protos x 128 dims), wave-private double buffer, counted vmcnt, 0 barriers
// in the K-loop.
__global__ __launch_bounds__(512, 4) void k_gemm_lsm(const float* __restrict__ qf,
                                                     const unsigned short* __restrict__ pb,
                                                     float* __restrict__ out) {
    extern __shared__ char smem[];
    const int tid  = threadIdx.x;
    const int w    = tid >> 6;
    const int lane = tid & 63;
    const int g    = lane >> 4;
    const int r16  = lane & 15;
    const size_t qbase = (size_t)blockIdx.x * BM;
    const char* pbB = (const char*)pb;
    char* myB = smem + SMEM_B + w * 8192;      // [2][4096] private to wave w

    // stage unit u: pass p=u&7, k-half h=u>>3; protos [p*128+w*16, +16) x dims [h*128,+128)
    // LDS [col][c16] linear; content pre-swizzled: pos holds global chunk pos^(col&7).
#define STAGE_UNIT(u, buf)                                                              \
    {                                                                                   \
        const int p_ = (u) & 7, h_ = (u) >> 3;                                          \
        _Pragma("unroll")                                                               \
        for (int i = 0; i < 4; ++i) {                                                   \
            const int e   = i * 64 + lane;                                              \
            const int col = e >> 4;                                                     \
            const int c16 = e & 15;                                                     \
            const char* src = pbB + ((size_t)(p_ * 128 + w * 16 + col) << 9)            \
                                  + (h_ << 8) + ((c16 ^ (col & 7)) << 4);               \
            gload_lds16(src, (buf) + i * 1024);                                         \
        }                                                                               \
    }

    // prologue: issue unit 0, then cooperative A-stage (16 rows x 256 dims)
    STAGE_UNIT(0, myB);
    {
        const int row = tid >> 5;            // 0..15
        const int seg = tid & 31;            // 0..31 (8 floats each)
        const float* qrow = qf + (qbase + row) * (size_t)DD + seg * 8;
        float4 f0 = *reinterpret_cast<const float4*>(qrow + 0);
        float4 f1 = *reinterpret_cast<const float4*>(qrow + 4);
        float ss = f0.x*f0.x + f0.y*f0.y + f0.z*f0.z + f0.w*f0.w
                 + f1.x*f1.x + f1.y*f1.y + f1.z*f1.z + f1.w*f1.w;
        ss += __shfl_xor(ss, 1); ss += __shfl_xor(ss, 2);
        ss += __shfl_xor(ss, 4); ss += __shfl_xor(ss, 8); ss += __shfl_xor(ss, 16);
        short8 h0;
        h0[0]=(short)f2bf(f0.x); h0[1]=(short)f2bf(f0.y); h0[2]=(short)f2bf(f0.z); h0[3]=(short)f2bf(f0.w);
        h0[4]=(short)f2bf(f1.x); h0[5]=(short)f2bf(f1.y); h0[6]=(short)f2bf(f1.z); h0[7]=(short)f2bf(f1.w);
        *reinterpret_cast<short8*>(smem + row * 512 + ((seg ^ (row & 7)) << 4)) = h0;
        if (seg == 0)
            reinterpret_cast<float*>(smem + SMEM_QI)[row] = 1.0f / fmaxf(sqrtf(ss), 1e-8f);
    }
    __syncthreads();   // drains unit-0 stage (vmcnt) + A writes (lgkm)

    // hoist A frags: a[h*4+kk] = query[r16][h*128 + kk*32 + g*8 ..+7]; 32 VGPRs
    short8 a[8];
#pragma unroll
    for (int ua = 0; ua < 8; ++ua) {
        const int chunk = ((ua >> 2) * 16 + (ua & 3) * 4 + g) ^ (r16 & 7);
        a[ua] = *reinterpret_cast<const short8*>(smem + r16 * 512 + chunk * 16);
    }

    f32x4 acc[8];
#pragma unroll
    for (int p = 0; p < 8; ++p) acc[p] = (f32x4){0.f, 0.f, 0.f, 0.f};

    // barrier-free per-wave pipeline over 16 stage-units (h-major order breaks
    // accumulator chains: consecutive units -> different acc[p])
#pragma unroll
    for (int u = 0; u < 16; ++u) {
        if (u + 1 < 16) {
            char* nbuf = myB + ((u + 1) & 1) * 4096;
            STAGE_UNIT(u + 1, nbuf);
            asm volatile("s_waitcnt vmcnt(4)" ::: "memory");   // unit u landed
        } else {
            asm volatile("s_waitcnt vmcnt(0)" ::: "memory");
        }
        const int p = u & 7, h = u >> 3;
        const char* bBase = myB + (u & 1) * 4096 + r16 * 256;
        __builtin_amdgcn_s_setprio(1);
#pragma unroll
        for (int kk = 0; kk < 4; ++kk) {
            short8 b = *reinterpret_cast<const short8*>(bBase + (((kk * 4 + g) ^ (r16 & 7)) << 4));
            acc[p] = __builtin_amdgcn_mfma_f32_16x16x32_bf16(b, a[h * 4 + kk], acc[p], 0, 0, 0);
        }
        __builtin_amdgcn_s_setprio(0);
    }

    // ---- epilogue: all 32 values in this thread belong to query row r16 ----
    const float qi = reinterpret_cast<const float*>(smem + SMEM_QI)[r16];
#pragma unroll
    for (int p = 0; p < 8; ++p)
#pragma unroll
        for (int j = 0; j < 4; ++j) acc[p][j] *= qi;

    float (*redM)[8] = reinterpret_cast<float(*)[8]>(smem + SMEM_REDM);
    float (*redS)[8] = reinterpret_cast<float(*)[8]>(smem + SMEM_REDS);

    float m = acc[0][0];
#pragma unroll
    for (int p = 0; p < 8; ++p)
#pragma unroll
        for (int j = 0; j < 4; ++j) m = fmaxf(m, acc[p][j]);
    m = fmaxf(m, __shfl_xor(m, 16));
    m = fmaxf(m, __shfl_xor(m, 32));
    if (lane < 16) redM[r16][w] = m;
    __syncthreads();
    float rowM = redM[r16][0];
#pragma unroll
    for (int k = 1; k < 8; ++k) rowM = fmaxf(rowM, redM[r16][k]);

    float s = 0.f;
#pragma unroll
    for (int p = 0; p < 8; ++p)
#pragma unroll
        for (int j = 0; j < 4; ++j) s += __expf(acc[p][j] - rowM);
    s += __shfl_xor(s, 16);
    s += __shfl_xor(s, 32);
    if (lane < 16) redS[r16][w] = s;
    __syncthreads();
    float rs = redS[r16][0];
#pragma unroll
    for (int k = 1; k < 8; ++k) rs += redS[r16][k];
    const float lse = rowM + __logf(rs);

    // stores straight from acc: one dwordx4 per pass (4 consecutive classes)
    float* orow = out + (qbase + r16) * (size_t)NC + w * 16 + g * 4;
#pragma unroll
    for (int p = 0; p < 8; ++p) {
        f32x4 v;
#pragma unroll
        for (int j = 0; j < 4; ++j) v[j] = acc[p][j] - lse;
        *reinterpret_cast<f32x4*>(orow + p * 128) = v;
    }
}

extern "C" void kernel_launch(void* const* d_in, const int* in_sizes, int n_in,
                              void* d_out, int out_size, void* d_ws, size_t ws_size,
                              hipStream_t stream) {
    const float* sf     = (const float*)d_in[0];
    const int*   labels = (const int*)d_in[1];
    const float* qf     = (const float*)d_in[2];
    float* out = (float*)d_out;

    char* ws = (char*)d_ws;
    float* rinv         = (float*)ws;                          // 256 KiB
    unsigned short* pb  = (unsigned short*)(ws + 262144);      // 512 KiB
    int* cnts           = (int*)(ws + 786432);                 // 4 KiB
    int* lists          = (int*)(ws + 790528);                 // 512 KiB

    hipFuncSetAttribute(reinterpret_cast<const void*>(k_gemm_lsm),
                        hipFuncAttributeMaxDynamicSharedMemorySize, SMEM_TOTAL);

    hipMemsetAsync(cnts, 0, NC * sizeof(int), stream);

    k_count<<<NS / 4, 256, 0, stream>>>(sf, labels, rinv, cnts, lists);

    float* outTail = out + (size_t)out_size - NC;
    k_proto<<<NC, 256, 0, stream>>>(sf, rinv, cnts, lists, pb, outTail);

    k_gemm_lsm<<<NQ / BM, 512, SMEM_TOTAL, stream>>>(qf, pb, out);
}

// Round 7
// 280.236 us; speedup vs baseline: 2.0060x; 1.4251x over previous
//
#include <hip/hip_runtime.h>
#include <hip/hip_bf16.h>

#define NS 65536
#define NQ 131072
#define DD 256
#define NC 1024
#define BM 32
#define LCAP 128

typedef __attribute__((ext_vector_type(8))) short short8;
typedef __attribute__((ext_vector_type(4))) float f32x4;

// LDS carve (bytes): B ring [2][32768] at 0; A [32][512] at 65536. Total 80 KB
// exactly -> 2 blocks/CU. After the A-hoist, the A region is dead and is
// overlaid with qinv (at +0) and the redM/redS tables (at +1024/+2048).
// After the K-loop, the B region is dead and is overlaid with a [16][1024]
// f32 output image (two passes).
#define SMEM_B     0
#define SMEM_A     65536
#define SMEM_TOTAL 81920

static __device__ __forceinline__ unsigned short f2bf(float f) {
    unsigned int u = __float_as_uint(f);
    u += 0x7fffu + ((u >> 16) & 1u);          // round-to-nearest-even
    return (unsigned short)(u >> 16);
}

static __device__ __forceinline__ void gload_lds16(const void* src, void* dst) {
    using GPtr = const __attribute__((address_space(1))) unsigned int*;
    using LPtr = __attribute__((address_space(3))) unsigned int*;
    GPtr g = reinterpret_cast<GPtr>(reinterpret_cast<uintptr_t>(src));
    LPtr l = reinterpret_cast<LPtr>(static_cast<unsigned int>(reinterpret_cast<uintptr_t>(dst)));
    __builtin_amdgcn_global_load_lds(g, l, 16, 0, 0);
}

// K1: one sf pass: per-row rinv (wave per row) + per-class compact row list.
__global__ __launch_bounds__(256) void k_count(const float* __restrict__ sf,
                                               const int* __restrict__ labels,
                                               float* __restrict__ rinv,
                                               int* __restrict__ cnts,
                                               int* __restrict__ lists) {
    const int row  = (blockIdx.x << 2) + (threadIdx.x >> 6);
    const int lane = threadIdx.x & 63;
    float4 v = *reinterpret_cast<const float4*>(sf + (size_t)row * DD + lane * 4);
    float ss = v.x*v.x + v.y*v.y + v.z*v.z + v.w*v.w;
#pragma unroll
    for (int off = 32; off; off >>= 1) ss += __shfl_xor(ss, off);
    if (lane == 0) {
        rinv[row] = 1.0f / fmaxf(sqrtf(ss), 1e-8f);
        const int lab = labels[row];
        const int slot = atomicAdd(&cnts[lab], 1);
        if (slot < LCAP) lists[lab * LCAP + slot] = row;
    }
}

// K2: block per class, gather listed rows, mean -> l2norm -> bf16 + arange tail.
__global__ __launch_bounds__(256) void k_proto(const float* __restrict__ sf,
                                               const float* __restrict__ rinv,
                                               const int* __restrict__ cnts,
                                               const int* __restrict__ lists,
                                               unsigned short* __restrict__ pb,
                                               float* __restrict__ outTail) {
    __shared__ float red[4];
    const int c = blockIdx.x;
    const int t = threadIdx.x;
    const int total = cnts[c];
    const int n = min(total, LCAP);
    float acc = 0.f;
    for (int j = 0; j < n; ++j) {
        const int row = lists[c * LCAP + j];
        acc += sf[(size_t)row * DD + t] * rinv[row];
    }
    const float m = acc / fmaxf((float)total, 1.0f);
    float ss = m * m;
#pragma unroll
    for (int off = 32; off; off >>= 1) ss += __shfl_xor(ss, off);
    if ((t & 63) == 0) red[t >> 6] = ss;
    __syncthreads();
    const float tot = red[0] + red[1] + red[2] + red[3];
    const float r = 1.0f / fmaxf(sqrtf(tot), 1e-8f);
    pb[(size_t)c * DD + t] = f2bf(m * r);
    if (t == 0) outTail[c] = (float)c;
}

// K3: fused GEMM + qnorm + log_softmax. 512 thr = 8 waves, BM=32 rows/block,
// 2 blocks/CU. Block-wide shared B staging: 16 units of 32 KB (512 classes x
// 32 dims), ring-2, counted vmcnt(4) + raw s_barrier (never drains to 0).
// Wave w: qg=w>>2 (16 q-rows), cs=w&3 (256 classes). Swapped MFMA:
// acc[n] = mfma(protoFrag, queryFrag, acc[n]) so thread (g,r16) holds
// logits[q = qg*16+r16][class = cs*256 + n*16 + g*4 + j].
__global__ __launch_bounds__(512, 4) void k_gemm_lsm(const float* __restrict__ qf,
                                                     const unsigned short* __restrict__ pb,
                                                     float* __restrict__ out) {
    extern __shared__ char smem[];
    const int tid  = threadIdx.x;
    const int w    = tid >> 6;
    const int lane = tid & 63;
    const int g    = lane >> 4;
    const int r16  = lane & 15;
    const int qg   = w >> 2;
    const int cs   = w & 3;
    const int mych = cs >> 1;
    const int cl0  = (cs & 1) * 256;
    const size_t qbase = (size_t)blockIdx.x * BM;
    const char* pbB = (const char*)pb;

    // ---- stage unit u (kk = u>>1, class-half = u&1) into B buf (u&1) ----
    // LDS layout: [512 c][64 B]; linear dest; SOURCE pre-swizzled so reads at
    // slot' = g ^ ((c>>1)&3) are conflict-free (2-way max).
#define STAGE(u)                                                                         \
    {                                                                                    \
        const int kk_ = (u) >> 1, ch_ = (u) & 1;                                         \
        char* dst_ = smem + SMEM_B + ((u) & 1) * 32768 + w * 4096;                       \
        _Pragma("unroll")                                                                \
        for (int i = 0; i < 4; ++i) {                                                    \
            const int e = w * 256 + i * 64 + lane;                                       \
            const int c = e >> 2, s = e & 3;                                             \
            const char* src = pbB + ((size_t)(ch_ * 512 + c) << 9) + (kk_ << 6)          \
                                  + ((s ^ ((c >> 1) & 3)) << 4);                         \
            gload_lds16(src, dst_ + i * 1024);                                           \
        }                                                                                \
    }

    // prologue: issue unit 0, then cooperative A-stage (32 rows x 256 dims)
    STAGE(0);
    float rinvLocal = 0.f;
    {
        const int row = tid >> 4;            // 0..31
        const int seg = tid & 15;            // 16 dims (64 B) each
        const float* qrow = qf + (qbase + row) * (size_t)DD + seg * 16;
        float4 f0 = *reinterpret_cast<const float4*>(qrow + 0);
        float4 f1 = *reinterpret_cast<const float4*>(qrow + 4);
        float4 f2 = *reinterpret_cast<const float4*>(qrow + 8);
        float4 f3 = *reinterpret_cast<const float4*>(qrow + 12);
        float ss = f0.x*f0.x + f0.y*f0.y + f0.z*f0.z + f0.w*f0.w
                 + f1.x*f1.x + f1.y*f1.y + f1.z*f1.z + f1.w*f1.w
                 + f2.x*f2.x + f2.y*f2.y + f2.z*f2.z + f2.w*f2.w
                 + f3.x*f3.x + f3.y*f3.y + f3.z*f3.z + f3.w*f3.w;
        ss += __shfl_xor(ss, 1); ss += __shfl_xor(ss, 2);
        ss += __shfl_xor(ss, 4); ss += __shfl_xor(ss, 8);
        rinvLocal = 1.0f / fmaxf(sqrtf(ss), 1e-8f);
        short8 h0, h1;
        h0[0]=(short)f2bf(f0.x); h0[1]=(short)f2bf(f0.y); h0[2]=(short)f2bf(f0.z); h0[3]=(short)f2bf(f0.w);
        h0[4]=(short)f2bf(f1.x); h0[5]=(short)f2bf(f1.y); h0[6]=(short)f2bf(f1.z); h0[7]=(short)f2bf(f1.w);
        h1[0]=(short)f2bf(f2.x); h1[1]=(short)f2bf(f2.y); h1[2]=(short)f2bf(f2.z); h1[3]=(short)f2bf(f2.w);
        h1[4]=(short)f2bf(f3.x); h1[5]=(short)f2bf(f3.y); h1[6]=(short)f2bf(f3.z); h1[7]=(short)f2bf(f3.w);
        const int x = row & 7;
        char* aRow = smem + SMEM_A + row * 512;
        *reinterpret_cast<short8*>(aRow + (((seg*2)     ^ x) << 4)) = h0;
        *reinterpret_cast<short8*>(aRow + (((seg*2 + 1) ^ x) << 4)) = h1;
    }
    __syncthreads();   // A staged (unit0 also drains here; prologue-only cost)

    // hoist query frags: a[kk] = q[qg*16+r16][kk*32 + g*8 ..+8]; 32 VGPRs
    short8 a[8];
    {
        const int row = qg * 16 + r16;
#pragma unroll
        for (int kk = 0; kk < 8; ++kk) {
            const int chunk = (kk * 4 + g) ^ (row & 7);
            a[kk] = *reinterpret_cast<const short8*>(smem + SMEM_A + row * 512 + chunk * 16);
        }
    }
    __syncthreads();   // all waves hoisted; A region is now free for overlays

    // qinv into dead A region
    if ((lane & 15) == 0)
        reinterpret_cast<float*>(smem + SMEM_A)[tid >> 4] = rinvLocal;

    f32x4 acc[16];
#pragma unroll
    for (int n = 0; n < 16; ++n) acc[n] = (f32x4){0.f, 0.f, 0.f, 0.f};

    // ---- main loop: 16 units, ring-2, counted vmcnt across barriers ----
#pragma unroll
    for (int u = 0; u < 16; ++u) {
        if (u + 1 < 16) {
            STAGE(u + 1);
            asm volatile("s_waitcnt vmcnt(4)" ::: "memory");   // unit u landed
        } else {
            asm volatile("s_waitcnt vmcnt(0)" ::: "memory");
        }
        asm volatile("s_barrier" ::: "memory");                 // everyone's unit u landed
        if (mych == (u & 1)) {
            const int kk = u >> 1;
            const char* base = smem + SMEM_B + (u & 1) * 32768;
            __builtin_amdgcn_s_setprio(1);
#pragma unroll
            for (int n = 0; n < 16; ++n) {
                const int c = cl0 + n * 16 + r16;
                short8 b = *reinterpret_cast<const short8*>(base + c * 64 + ((g ^ ((c >> 1) & 3)) << 4));
                acc[n] = __builtin_amdgcn_mfma_f32_16x16x32_bf16(b, a[kk], acc[n], 0, 0, 0);
            }
            __builtin_amdgcn_s_setprio(0);
        }
    }
    __syncthreads();   // K done; B region becomes the output image

    // ---- epilogue: qinv scale + row log_softmax ----
    float* qinvLds = reinterpret_cast<float*>(smem + SMEM_A);
    float* redM = reinterpret_cast<float*>(smem + SMEM_A + 1024);   // [32][4]
    float* redS = reinterpret_cast<float*>(smem + SMEM_A + 2048);   // [32][4]
    const int myrow = qg * 16 + r16;
    const float qi = qinvLds[myrow];

#pragma unroll
    for (int n = 0; n < 16; ++n)
#pragma unroll
        for (int j = 0; j < 4; ++j) acc[n][j] *= qi;

    float m = acc[0][0];
#pragma unroll
    for (int n = 0; n < 16; ++n)
#pragma unroll
        for (int j = 0; j < 4; ++j) m = fmaxf(m, acc[n][j]);
    m = fmaxf(m, __shfl_xor(m, 16));
    m = fmaxf(m, __shfl_xor(m, 32));
    if (lane < 16) redM[myrow * 4 + cs] = m;
    __syncthreads();
    float rowM = redM[myrow * 4 + 0];
#pragma unroll
    for (int k = 1; k < 4; ++k) rowM = fmaxf(rowM, redM[myrow * 4 + k]);

    float s = 0.f;
#pragma unroll
    for (int n = 0; n < 16; ++n)
#pragma unroll
        for (int j = 0; j < 4; ++j) s += __expf(acc[n][j] - rowM);
    s += __shfl_xor(s, 16);
    s += __shfl_xor(s, 32);
    if (lane < 16) redS[myrow * 4 + cs] = s;
    __syncthreads();
    float rs = redS[myrow * 4 + 0];
#pragma unroll
    for (int k = 1; k < 4; ++k) rs += redS[myrow * 4 + k];
    const float lse = rowM + __logf(rs);

    // ---- stores via [16][1024] f32 image in dead B region, 2 passes ----
#pragma unroll
    for (int pass = 0; pass < 2; ++pass) {
        if (qg == pass) {
#pragma unroll
            for (int n = 0; n < 16; ++n) {
                f32x4 v;
#pragma unroll
                for (int j = 0; j < 4; ++j) v[j] = acc[n][j] - lse;
                const int slot = cs * 64 + n * 4 + g;           // 16B slot in row
                *reinterpret_cast<f32x4*>(smem + r16 * 4096 + ((slot ^ (r16 & 7)) << 4)) = v;
            }
        }
        __syncthreads();
        {
            const int row = tid >> 5;        // 0..15
            const int s0  = tid & 31;
            float* gout = out + (qbase + pass * 16 + row) * (size_t)NC;
#pragma unroll
            for (int p = 0; p < 8; ++p) {
                const int slot = p * 32 + s0;
                f32x4 v = *reinterpret_cast<const f32x4*>(smem + row * 4096 + ((slot ^ (row & 7)) << 4));
                *reinterpret_cast<f32x4*>(gout + slot * 4) = v;
            }
        }
        if (pass == 0) __syncthreads();
    }
}

extern "C" void kernel_launch(void* const* d_in, const int* in_sizes, int n_in,
                              void* d_out, int out_size, void* d_ws, size_t ws_size,
                              hipStream_t stream) {
    const float* sf     = (const float*)d_in[0];
    const int*   labels = (const int*)d_in[1];
    const float* qf     = (const float*)d_in[2];
    float* out = (float*)d_out;

    char* ws = (char*)d_ws;
    float* rinv         = (float*)ws;                          // 256 KiB
    unsigned short* pb  = (unsigned short*)(ws + 262144);      // 512 KiB
    int* cnts           = (int*)(ws + 786432);                 // 4 KiB
    int* lists          = (int*)(ws + 790528);                 // 512 KiB

    hipFuncSetAttribute(reinterpret_cast<const void*>(k_gemm_lsm),
                        hipFuncAttributeMaxDynamicSharedMemorySize, SMEM_TOTAL);

    hipMemsetAsync(cnts, 0, NC * sizeof(int), stream);

    k_count<<<NS / 4, 256, 0, stream>>>(sf, labels, rinv, cnts, lists);

    float* outTail = out + (size_t)out_size - NC;
    k_proto<<<NC, 256, 0, stream>>>(sf, rinv, cnts, lists, pb, outTail);

    k_gemm_lsm<<<NQ / BM, 512, SMEM_TOTAL, stream>>>(qf, pb, out);
}

// Round 8
// 279.327 us; speedup vs baseline: 2.0126x; 1.0033x over previous
//
#include <hip/hip_runtime.h>
#include <hip/hip_bf16.h>

#define NS 65536
#define NQ 131072
#define DD 256
#define NC 1024
#define BM 32
#define LCAP 128

typedef __attribute__((ext_vector_type(8))) short short8;
typedef __attribute__((ext_vector_type(4))) float f32x4;

// LDS carve (bytes): B ring 4 x 16384 at 0; A [32][512] at 65536. Total 80 KB
// -> 2 blocks/CU. After A-hoist the A region is overlaid with qinv(+0),
// redM(+1024), redS(+2048). After the K-loop the B ring is overlaid with a
// [16][1024] f32 output image (two passes).
#define SMEM_B     0
#define SMEM_A     65536
#define SMEM_TOTAL 81920

static __device__ __forceinline__ unsigned short f2bf(float f) {
    unsigned int u = __float_as_uint(f);
    u += 0x7fffu + ((u >> 16) & 1u);          // round-to-nearest-even
    return (unsigned short)(u >> 16);
}

static __device__ __forceinline__ void gload_lds16(const void* src, void* dst) {
    using GPtr = const __attribute__((address_space(1))) unsigned int*;
    using LPtr = __attribute__((address_space(3))) unsigned int*;
    GPtr g = reinterpret_cast<GPtr>(reinterpret_cast<uintptr_t>(src));
    LPtr l = reinterpret_cast<LPtr>(static_cast<unsigned int>(reinterpret_cast<uintptr_t>(dst)));
    __builtin_amdgcn_global_load_lds(g, l, 16, 0, 0);
}

// K1: one sf pass: per-row rinv (wave per row) + per-class compact row list.
__global__ __launch_bounds__(256) void k_count(const float* __restrict__ sf,
                                               const int* __restrict__ labels,
                                               float* __restrict__ rinv,
                                               int* __restrict__ cnts,
                                               int* __restrict__ lists) {
    const int row  = (blockIdx.x << 2) + (threadIdx.x >> 6);
    const int lane = threadIdx.x & 63;
    float4 v = *reinterpret_cast<const float4*>(sf + (size_t)row * DD + lane * 4);
    float ss = v.x*v.x + v.y*v.y + v.z*v.z + v.w*v.w;
#pragma unroll
    for (int off = 32; off; off >>= 1) ss += __shfl_xor(ss, off);
    if (lane == 0) {
        rinv[row] = 1.0f / fmaxf(sqrtf(ss), 1e-8f);
        const int lab = labels[row];
        const int slot = atomicAdd(&cnts[lab], 1);
        if (slot < LCAP) lists[lab * LCAP + slot] = row;
    }
}

// K2: block per class, gather listed rows, mean -> l2norm -> bf16 + arange tail.
__global__ __launch_bounds__(256) void k_proto(const float* __restrict__ sf,
                                               const float* __restrict__ rinv,
                                               const int* __restrict__ cnts,
                                               const int* __restrict__ lists,
                                               unsigned short* __restrict__ pb,
                                               float* __restrict__ outTail) {
    __shared__ float red[4];
    const int c = blockIdx.x;
    const int t = threadIdx.x;
    const int total = cnts[c];
    const int n = min(total, LCAP);
    float acc = 0.f;
    for (int j = 0; j < n; ++j) {
        const int row = lists[c * LCAP + j];
        acc += sf[(size_t)row * DD + t] * rinv[row];
    }
    const float m = acc / fmaxf((float)total, 1.0f);
    float ss = m * m;
#pragma unroll
    for (int off = 32; off; off >>= 1) ss += __shfl_xor(ss, off);
    if ((t & 63) == 0) red[t >> 6] = ss;
    __syncthreads();
    const float tot = red[0] + red[1] + red[2] + red[3];
    const float r = 1.0f / fmaxf(sqrtf(tot), 1e-8f);
    pb[(size_t)c * DD + t] = f2bf(m * r);
    if (t == 0) outTail[c] = (float)c;
}

// K3: fused GEMM + qnorm + log_softmax. 512 thr = 8 waves (qg = w>>2, cq = w&3),
// BM=32, 2 blocks/CU. 32 stage-units of 16 KB (unit u: kk=u>>2 dims, cu=u&3
// classes [cu*256,+256) x dims [kk*32,+32)), ring-4, STAGE issued AFTER the
// barrier (race-free: buf[(u+3)&3]=buf[(u-1)&3], whose readers all passed the
// barrier), counted vmcnt(4/2/0). Every wave consumes every unit: 4 MFMA on 4
// distinct accumulators. Thread (qg,cq,g,r16) reg (n,j) holds
// logits[q=qg*16+r16][class = n*64 + cq*16 + g*4 + j].
__global__ __launch_bounds__(512, 4) void k_gemm_lsm(const float* __restrict__ qf,
                                                     const unsigned short* __restrict__ pb,
                                                     float* __restrict__ out) {
    extern __shared__ char smem[];
    const int tid  = threadIdx.x;
    const int w    = tid >> 6;
    const int lane = tid & 63;
    const int g    = lane >> 4;
    const int r16  = lane & 15;
    const int qg   = w >> 2;
    const int cq   = w & 3;
    const size_t qbase = (size_t)blockIdx.x * BM;
    const char* pbB = (const char*)pb;

    // stage unit u: LDS [256 c][64 B] linear dest; SOURCE pre-swizzled so reads
    // at slot' = g ^ (c&3) are balanced (involution: s ^ (c&3)).
#define STAGE(u)                                                                         \
    {                                                                                    \
        const int kk_ = (u) >> 2, cu_ = (u) & 3;                                         \
        char* dst_ = smem + SMEM_B + ((u) & 3) * 16384 + w * 2048;                       \
        _Pragma("unroll")                                                                \
        for (int i = 0; i < 2; ++i) {                                                    \
            const int e = w * 128 + i * 64 + lane;                                       \
            const int c = e >> 2, s = e & 3;                                             \
            const char* src = pbB + ((size_t)(cu_ * 256 + c) << 9) + (kk_ << 6)          \
                                  + ((s ^ (c & 3)) << 4);                                \
            gload_lds16(src, dst_ + i * 1024);                                           \
        }                                                                                \
    }

    // prologue: issue units 0..2, then cooperative A-stage (32 rows x 256 dims)
    STAGE(0);
    STAGE(1);
    STAGE(2);
    float rinvLocal = 0.f;
    {
        const int row = tid >> 4;            // 0..31
        const int seg = tid & 15;            // 16 dims (64 B) each
        const float* qrow = qf + (qbase + row) * (size_t)DD + seg * 16;
        float4 f0 = *reinterpret_cast<const float4*>(qrow + 0);
        float4 f1 = *reinterpret_cast<const float4*>(qrow + 4);
        float4 f2 = *reinterpret_cast<const float4*>(qrow + 8);
        float4 f3 = *reinterpret_cast<const float4*>(qrow + 12);
        float ss = f0.x*f0.x + f0.y*f0.y + f0.z*f0.z + f0.w*f0.w
                 + f1.x*f1.x + f1.y*f1.y + f1.z*f1.z + f1.w*f1.w
                 + f2.x*f2.x + f2.y*f2.y + f2.z*f2.z + f2.w*f2.w
                 + f3.x*f3.x + f3.y*f3.y + f3.z*f3.z + f3.w*f3.w;
        ss += __shfl_xor(ss, 1); ss += __shfl_xor(ss, 2);
        ss += __shfl_xor(ss, 4); ss += __shfl_xor(ss, 8);
        rinvLocal = 1.0f / fmaxf(sqrtf(ss), 1e-8f);
        short8 h0, h1;
        h0[0]=(short)f2bf(f0.x); h0[1]=(short)f2bf(f0.y); h0[2]=(short)f2bf(f0.z); h0[3]=(short)f2bf(f0.w);
        h0[4]=(short)f2bf(f1.x); h0[5]=(short)f2bf(f1.y); h0[6]=(short)f2bf(f1.z); h0[7]=(short)f2bf(f1.w);
        h1[0]=(short)f2bf(f2.x); h1[1]=(short)f2bf(f2.y); h1[2]=(short)f2bf(f2.z); h1[3]=(short)f2bf(f2.w);
        h1[4]=(short)f2bf(f3.x); h1[5]=(short)f2bf(f3.y); h1[6]=(short)f2bf(f3.z); h1[7]=(short)f2bf(f3.w);
        const int x = row & 7;
        char* aRow = smem + SMEM_A + row * 512;
        *reinterpret_cast<short8*>(aRow + (((seg*2)     ^ x) << 4)) = h0;
        *reinterpret_cast<short8*>(aRow + (((seg*2 + 1) ^ x) << 4)) = h1;
    }
    __syncthreads();   // full drain: units 0-2 + A all in LDS (prologue only)

    // hoist query frags: a[kk] = q[qg*16+r16][kk*32 + g*8 ..+8]; 32 VGPRs
    short8 a[8];
    {
        const int row = qg * 16 + r16;
#pragma unroll
        for (int kk = 0; kk < 8; ++kk) {
            const int chunk = (kk * 4 + g) ^ (row & 7);
            a[kk] = *reinterpret_cast<const short8*>(smem + SMEM_A + row * 512 + chunk * 16);
        }
    }
    __syncthreads();   // all waves hoisted; A region free for overlays

    if ((lane & 15) == 0)
        reinterpret_cast<float*>(smem + SMEM_A)[tid >> 4] = rinvLocal;

    f32x4 acc[16];
#pragma unroll
    for (int n = 0; n < 16; ++n) acc[n] = (f32x4){0.f, 0.f, 0.f, 0.f};

    // ---- main loop: 32 units, ring-4, stage-after-barrier, counted vmcnt ----
#pragma unroll
    for (int u = 0; u < 32; ++u) {
        if (u <= 29)      { asm volatile("s_waitcnt vmcnt(4)" ::: "memory"); }
        else if (u == 30) { asm volatile("s_waitcnt vmcnt(2)" ::: "memory"); }
        else              { asm volatile("s_waitcnt vmcnt(0)" ::: "memory"); }
        asm volatile("s_barrier" ::: "memory");
        if (u + 3 < 32) STAGE(u + 3);
        const int kk = u >> 2, cu = u & 3;
        const char* base = smem + SMEM_B + (u & 3) * 16384;
        __builtin_amdgcn_s_setprio(1);
#pragma unroll
        for (int np = 0; np < 4; ++np) {
            const int cl = np * 64 + cq * 16 + r16;          // class within unit
            short8 b = *reinterpret_cast<const short8*>(base + cl * 64 + ((g ^ (cl & 3)) << 4));
            acc[cu * 4 + np] = __builtin_amdgcn_mfma_f32_16x16x32_bf16(b, a[kk], acc[cu * 4 + np], 0, 0, 0);
        }
        __builtin_amdgcn_s_setprio(0);
    }
    __syncthreads();   // K done; B ring becomes the output image

    // ---- epilogue: qinv scale + row log_softmax ----
    float* qinvLds = reinterpret_cast<float*>(smem + SMEM_A);
    float* redM = reinterpret_cast<float*>(smem + SMEM_A + 1024);   // [32][4]
    float* redS = reinterpret_cast<float*>(smem + SMEM_A + 2048);   // [32][4]
    const int myrow = qg * 16 + r16;
    const float qi = qinvLds[myrow];

#pragma unroll
    for (int n = 0; n < 16; ++n)
#pragma unroll
        for (int j = 0; j < 4; ++j) acc[n][j] *= qi;

    float m = acc[0][0];
#pragma unroll
    for (int n = 0; n < 16; ++n)
#pragma unroll
        for (int j = 0; j < 4; ++j) m = fmaxf(m, acc[n][j]);
    m = fmaxf(m, __shfl_xor(m, 16));
    m = fmaxf(m, __shfl_xor(m, 32));
    if (lane < 16) redM[myrow * 4 + cq] = m;
    __syncthreads();
    float rowM = redM[myrow * 4 + 0];
#pragma unroll
    for (int k = 1; k < 4; ++k) rowM = fmaxf(rowM, redM[myrow * 4 + k]);

    float s = 0.f;
#pragma unroll
    for (int n = 0; n < 16; ++n)
#pragma unroll
        for (int j = 0; j < 4; ++j) s += __expf(acc[n][j] - rowM);
    s += __shfl_xor(s, 16);
    s += __shfl_xor(s, 32);
    if (lane < 16) redS[myrow * 4 + cq] = s;
    __syncthreads();
    float rs = redS[myrow * 4 + 0];
#pragma unroll
    for (int k = 1; k < 4; ++k) rs += redS[myrow * 4 + k];
    const float lse = rowM + __logf(rs);

    // ---- stores via [16][1024] f32 image in dead B ring, 2 passes ----
#pragma unroll
    for (int pass = 0; pass < 2; ++pass) {
        if (qg == pass) {
#pragma unroll
            for (int n = 0; n < 16; ++n) {
                f32x4 v;
#pragma unroll
                for (int j = 0; j < 4; ++j) v[j] = acc[n][j] - lse;
                const int slot = n * 16 + cq * 4 + g;           // 16B slot in row
                *reinterpret_cast<f32x4*>(smem + r16 * 4096 + ((slot ^ (r16 & 7)) << 4)) = v;
            }
        }
        __syncthreads();
        {
            const int row = tid >> 5;        // 0..15
            const int s0  = tid & 31;
            float* gout = out + (qbase + pass * 16 + row) * (size_t)NC;
#pragma unroll
            for (int p = 0; p < 8; ++p) {
                const int slot = p * 32 + s0;
                f32x4 v = *reinterpret_cast<const f32x4*>(smem + row * 4096 + ((slot ^ (row & 7)) << 4));
                *reinterpret_cast<f32x4*>(gout + slot * 4) = v;
            }
        }
        if (pass == 0) __syncthreads();
    }
}

extern "C" void kernel_launch(void* const* d_in, const int* in_sizes, int n_in,
                              void* d_out, int out_size, void* d_ws, size_t ws_size,
                              hipStream_t stream) {
    const float* sf     = (const float*)d_in[0];
    const int*   labels = (const int*)d_in[1];
    const float* qf     = (const float*)d_in[2];
    float* out = (float*)d_out;

    char* ws = (char*)d_ws;
    float* rinv         = (float*)ws;                          // 256 KiB
    unsigned short* pb  = (unsigned short*)(ws + 262144);      // 512 KiB
    int* cnts           = (int*)(ws + 786432);                 // 4 KiB
    int* lists          = (int*)(ws + 790528);                 // 512 KiB

    hipFuncSetAttribute(reinterpret_cast<const void*>(k_gemm_lsm),
                        hipFuncAttributeMaxDynamicSharedMemorySize, SMEM_TOTAL);

    hipMemsetAsync(cnts, 0, NC * sizeof(int), stream);

    k_count<<<NS / 4, 256, 0, stream>>>(sf, labels, rinv, cnts, lists);

    float* outTail = out + (size_t)out_size - NC;
    k_proto<<<NC, 256, 0, stream>>>(sf, rinv, cnts, lists, pb, outTail);

    k_gemm_lsm<<<NQ / BM, 512, SMEM_TOTAL, stream>>>(qf, pb, out);
}